// Round 14
// baseline (277.160 us; speedup 1.0000x reference)
//
#include <hip/hip_runtime.h>
#include <hip/hip_bf16.h>

// B=2, T=2048, DM=1024, H=16, DK=DV=64
// ws layout (56 MB, Xb slot now unused):
//   [0,2)MB  Wqt bf16 [n=h*64+k][d]   [2,4) Wkt   [4,6) Wvt   [6,8) Wot [n=DM][k=H*DV]
//   [8,16)   AO bf16 [t][h*64+dv]     (written by attn)
//   [32,40)  Qb bf16 [b][h][t][dk]
//   [40,48)  Kt2 bf16 [bh][64 ktile][s:1][dc:1][c:16][q4:4][j:8]  (K A-frag tiled)
//   [48,56)  Vt2 bf16 [bh][64 ktile][64 dv][32 k']  (V^T tiled, key-permuted sigma)
// x-cast kernel ELIMINATED: proj reads f32 X directly into REGISTERS
// (R12's failed variant used ds_write staging -> 3.1M bank conflicts; this
// one has zero LDS writes on the X path).

typedef __attribute__((ext_vector_type(8))) short short8;
typedef __attribute__((ext_vector_type(4))) short short4v;
typedef __attribute__((ext_vector_type(4))) float f32x4;
typedef __attribute__((ext_vector_type(4))) int i32x4;

__device__ __forceinline__ short f2bf(float f) {
  union { float f; unsigned u; } v; v.f = f;
  unsigned r = v.u + 0x7FFFu + ((v.u >> 16) & 1u);  // RNE
  return (short)(r >> 16);
}

#define GLD_LDS(g, l) __builtin_amdgcn_global_load_lds( \
    (const __attribute__((address_space(1))) void*)(g), \
    (__attribute__((address_space(3))) void*)(l), 16, 0, 0)

// ---------------- prep: W transposes only (R12-validated) ------------------
__global__ __launch_bounds__(256) void prep_w(
    const float* __restrict__ wq, const float* __restrict__ wk,
    const float* __restrict__ wv, const float* __restrict__ wo,
    short* __restrict__ Wall, short* __restrict__ Wot)
{
  const int bx = blockIdx.x, tid = threadIdx.x;
  __shared__ float Lt[64][65];
  if (bx < 768) {                        // ---- Wq/k/v transpose (256 per z)
    int z = bx >> 8, inner = bx & 255;
    const float* w = z == 0 ? wq : (z == 1 ? wk : wv);
    short* Wt = Wall + (size_t)z * 1048576;
    int h = inner >> 4, d0 = (inner & 15) * 64;
#pragma unroll
    for (int it = 0; it < 4; it++) {
      int e = tid + it * 256;
      int dl = e >> 4, k4 = (e & 15) * 4;
      f32x4 v = *(const f32x4*)(w + ((size_t)(h * 1024 + d0 + dl) * 64) + k4);
#pragma unroll
      for (int j = 0; j < 4; j++) Lt[dl][k4 + j] = v[j];
    }
    __syncthreads();
#pragma unroll
    for (int it = 0; it < 4; it++) {
      int e = tid + it * 256;
      int kl = e >> 4, dq = e & 15;
      short4v s;
#pragma unroll
      for (int j = 0; j < 4; j++) s[j] = f2bf(Lt[dq * 4 + j][kl]);
      *(short4v*)(Wt + (size_t)(h * 64 + kl) * 1024 + d0 + dq * 4) = s;
    }
  } else {                               // ---- Wo transpose (256 blocks)
    int bz = bx - 768;
    int k0 = (bz >> 4) * 64, n0 = (bz & 15) * 64;
#pragma unroll
    for (int it = 0; it < 4; it++) {
      int e = tid + it * 256;
      int kl = e >> 4, n4 = (e & 15) * 4;
      f32x4 v = *(const f32x4*)(wo + (size_t)(k0 + kl) * 1024 + n0 + n4);
#pragma unroll
      for (int j = 0; j < 4; j++) Lt[kl][n4 + j] = v[j];
    }
    __syncthreads();
#pragma unroll
    for (int it = 0; it < 4; it++) {
      int e = tid + it * 256;
      int nl = e >> 4, kq = e & 15;
      short4v s;
#pragma unroll
      for (int j = 0; j < 4; j++) s[j] = f2bf(Lt[kq * 4 + j][nl]);
      *(short4v*)(Wot + (size_t)(n0 + nl) * 1024 + k0 + kq * 4) = s;
    }
  }
}

// ---------------- QKV projection v5: f32 X in REGISTERS --------------------
// R13's dbuf sync skeleton (proven) with the Bl side replaced by registers:
//  - per phase, each wave loads ONLY its own quadrant's X fragments (16
//    f32x4 = exact elements the old Bl reads produced, index-verified)
//  - PCOMP converts xr -> bf16 frags via cvt_pk (R12-validated numerics),
//    then re-issues next phase's X loads (latency hidden under 32 MFMAs +
//    the drain), then MFMAs. Single xr buffer, no runtime indexing.
//  - zero LDS writes on the X path (R12's conflict mechanism is gone);
//    LDS halves to 32 KB, GLD/phase halves to 4.
// Eliminates the x-cast kernel + its 72 MB HBM round-trip.
__global__ __launch_bounds__(256) void proj_qkv5(
    const float* __restrict__ xq, const float* __restrict__ xk,
    const float* __restrict__ xv, const short* __restrict__ Wall,
    short* __restrict__ Qb, short* __restrict__ Kt2, short* __restrict__ Vt2)
{
  const int z = blockIdx.z;
  const float* X  = z == 0 ? xq : (z == 1 ? xk : xv);
  const short* Wt = Wall + (size_t)z * 1048576;

  const int t0 = blockIdx.x * 128;   // 32
  const int n0 = blockIdx.y * 128;   // 8
  const int tid = threadIdx.x, w = tid >> 6, lane = tid & 63;
  const int c = lane & 15, q4 = lane >> 4;
  const int wn = (w & 1) * 64, wt = (w >> 1) * 64;
  const int srow = lane >> 2, scol = (lane & 3) * 8;

  __shared__ __align__(16) short Al[2][2][4096];   // 32 KB (Wt side only)

  f32x4 acc[4][4] = {};
  f32x4 xr[2][4][2];   // [sub][frag][half]: X f32 for ONE phase (own quadrant)

#define PSTAGE_A(BUF, K0) do { \
    _Pragma("unroll") \
    for (int sub = 0; sub < 2; sub++) { \
      _Pragma("unroll") \
      for (int i = 0; i < 2; i++) { \
        int rg = (w * 2 + i) * 16; \
        GLD_LDS(Wt + (size_t)(n0 + rg + srow) * 1024 + (K0) + sub * 32 + scol, &Al[BUF][sub][rg * 32]); \
      } \
    } \
  } while (0)

  // X frag loads: element m of old bfr[sub][f] was
  // X[t0+wt+f*16+c][K0+sub*32+q4*8+m] -- load those 8 f32 as two f32x4
#define XLOAD(K0) do { \
    _Pragma("unroll") \
    for (int sub = 0; sub < 2; sub++) { \
      _Pragma("unroll") \
      for (int f = 0; f < 4; f++) { \
        const float* xs = X + (size_t)(t0 + wt + f * 16 + c) * 1024 + (K0) + sub * 32 + q4 * 8; \
        xr[sub][f][0] = *(const f32x4*)(xs); \
        xr[sub][f][1] = *(const f32x4*)(xs + 4); \
      } \
    } \
  } while (0)

  // convert xr -> bf16 frags, re-issue XLOAD(NK), then MFMA block
#define PCOMP(BUF, NK) do { \
    short8 xb[2][4]; \
    _Pragma("unroll") \
    for (int sub = 0; sub < 2; sub++) { \
      _Pragma("unroll") \
      for (int f = 0; f < 4; f++) { \
        unsigned p0, p1, p2, p3; \
        asm("v_cvt_pk_bf16_f32 %0, %1, %2" : "=v"(p0) : "v"(xr[sub][f][0][0]), "v"(xr[sub][f][0][1])); \
        asm("v_cvt_pk_bf16_f32 %0, %1, %2" : "=v"(p1) : "v"(xr[sub][f][0][2]), "v"(xr[sub][f][0][3])); \
        asm("v_cvt_pk_bf16_f32 %0, %1, %2" : "=v"(p2) : "v"(xr[sub][f][1][0]), "v"(xr[sub][f][1][1])); \
        asm("v_cvt_pk_bf16_f32 %0, %1, %2" : "=v"(p3) : "v"(xr[sub][f][1][2]), "v"(xr[sub][f][1][3])); \
        union { i32x4 iv; short8 s; } pk; \
        pk.iv[0] = (int)p0; pk.iv[1] = (int)p1; pk.iv[2] = (int)p2; pk.iv[3] = (int)p3; \
        xb[sub][f] = pk.s; \
      } \
    } \
    XLOAD(NK);                         /* xr dead after cvt; reload for next */ \
    _Pragma("unroll") \
    for (int sub = 0; sub < 2; sub++) { \
      short8 wf[4]; \
      _Pragma("unroll") \
      for (int i = 0; i < 4; i++) \
        wf[i] = *(const short8*)(&Al[BUF][sub][(wn + i * 16 + c) * 32 + q4 * 8]); \
      if (z != 2) { \
        _Pragma("unroll") \
        for (int i = 0; i < 4; i++) \
          _Pragma("unroll") \
          for (int j = 0; j < 4; j++) \
            acc[i][j] = __builtin_amdgcn_mfma_f32_16x16x32_bf16(wf[i], xb[sub][j], acc[i][j], 0, 0, 0); \
      } else { \
        _Pragma("unroll") \
        for (int i = 0; i < 4; i++) \
          _Pragma("unroll") \
          for (int j = 0; j < 4; j++) \
            acc[i][j] = __builtin_amdgcn_mfma_f32_16x16x32_bf16(xb[sub][i], wf[j], acc[i][j], 0, 0, 0); \
      } \
    } \
  } while (0)

  XLOAD(0);                             // phase-0 X in flight
  PSTAGE_A(0, 0);
  asm volatile("s_waitcnt vmcnt(0)" ::: "memory");
  __syncthreads();                      // Al[0] + xr(0) ready
  int cur = 0;
  for (int p = 0; p < 15; ++p) {
    PSTAGE_A(cur ^ 1, (p + 1) * 64);    // stage next Wt while computing
    PCOMP(cur, (p + 1) * 64);           // cvt xr(p), XLOAD(p+1), 32 MFMAs
    asm volatile("s_waitcnt vmcnt(0)" ::: "memory");
    __syncthreads();
    cur ^= 1;
  }
  PCOMP(cur, 0);                        // final: dummy XLOAD(0), never used
#undef PSTAGE_A
#undef XLOAD
#undef PCOMP

  if (z != 2) {
#pragma unroll
    for (int i = 0; i < 4; i++)
#pragma unroll
      for (int j = 0; j < 4; j++) {
        int n = n0 + wn + i * 16 + q4 * 4;     // h*64 + d base (+4 consecutive)
        int trow = t0 + wt + j * 16 + c;
        int b = trow >> 11, t = trow & 2047;
        int h = n >> 6, cc = n & 63;
        int bh = b * 16 + h;
        f32x4 v = acc[i][j];
        short4v pk;
#pragma unroll
        for (int r = 0; r < 4; r++) pk[r] = f2bf(v[r]);
        if (z == 0) {
          *(short4v*)(Qb + (size_t)(bh * 2048 + t) * 64 + cc) = pk;
        } else {
          // Kt2: cc%4==0 -> the 4 d-values share chunk bits -> one short4
          int t5 = t & 31, s_ = t5 >> 4, c_ = t5 & 15;
          size_t base = (size_t)bh * 131072 + (t >> 5) * 2048;
          size_t off = base + ((s_ * 2 + (cc >> 5)) * 16 + c_) * 32 +
                       ((cc >> 3) & 3) * 8 + (cc & 7);
          *(short4v*)(Kt2 + off) = pk;
        }
      }
  } else {
    // swapped operands: output quad runs along t (t%4==0), col = n
#pragma unroll
    for (int i = 0; i < 4; i++)
#pragma unroll
      for (int j = 0; j < 4; j++) {
        int tq = t0 + wt + i * 16 + q4 * 4;    // 4 consecutive keys
        int n = n0 + wn + j * 16 + c;
        int b = tq >> 11, t = tq & 2047;
        int h = n >> 6, cc = n & 63;
        int bh = b * 16 + h;
        int t5 = t & 31;                        // t5 % 4 == 0
        int kpb = ((t5 >> 2) & 3) * 8 + ((t5 >> 4) & 1) * 4;  // kp(t5+r)=kpb+r
        size_t base = (size_t)bh * 131072 + (t >> 5) * 2048;
        f32x4 v = acc[i][j];
        short4v pk;
#pragma unroll
        for (int r = 0; r < 4; r++) pk[r] = f2bf(v[r]);
        *(short4v*)(Vt2 + base + (size_t)cc * 32 + kpb) = pk;
      }
  }
}

// ---------------- fused attention v14 (R9/R11/R13-proven, 52.1us) ----------
__global__ __launch_bounds__(256, 2) void attn14(
    const short* __restrict__ Qb, const short* __restrict__ Kt2,
    const short* __restrict__ Vt2, const float* __restrict__ mask,
    short* __restrict__ AO)
{
  const int bh = blockIdx.x;
  const int tblk = blockIdx.y;
  const int b = bh >> 4, h = bh & 15;
  const short* Qh = Qb  + (size_t)bh * 131072;
  const short* Kh = Kt2 + (size_t)bh * 131072;
  const short* Vh = Vt2 + (size_t)bh * 131072;

  const int tid = threadIdx.x, w = tid >> 6, lane = tid & 63;
  const int c = lane & 15, q4 = lane >> 4;
  const int qrow0 = tblk * 128 + w * 32;

  // LDS: 2 phase-buffers x 2 tiles x [K segs 0..3 | V segs 4..7] = 32 KB
  __shared__ __align__(16) short KV2[2][8192];
  __shared__ __align__(16) float cmL[2048];     // mask * log2e/64
  __shared__ __align__(16) float cbL[2048];     // (mask-1) * 240

  const int ch = c * 4 + q4;
  const int rdo = (ch ^ ((ch >> 3) & 3)) * 8;   // swizzled ds_read offset
  const int sch = (lane ^ ((lane >> 3) & 3)) * 8;

  // mask coefficient precompute (8 elems/thread)
  {
    const float LOG2E_64c = 1.44269504088896f * 0.015625f;
    f32x4 m0 = *(const f32x4*)(mask + b * 2048 + tid * 8);
    f32x4 m1 = *(const f32x4*)(mask + b * 2048 + tid * 8 + 4);
    *(f32x4*)(&cmL[tid * 8])     = m0 * LOG2E_64c;
    *(f32x4*)(&cmL[tid * 8 + 4]) = m1 * LOG2E_64c;
    *(f32x4*)(&cbL[tid * 8])     = (m0 - 1.0f) * 240.0f;
    *(f32x4*)(&cbL[tid * 8 + 4]) = (m1 - 1.0f) * 240.0f;
  }

  // Q fragments for the whole loop (B-operand: n=qrow=c, k=q4*8+j)
  short8 qa[2][2];
#pragma unroll
  for (int u = 0; u < 2; u++)
#pragma unroll
    for (int dc = 0; dc < 2; dc++)
      qa[u][dc] = *(const short8*)(Qh + (size_t)(qrow0 + u * 16 + c) * 64 + dc * 32 + q4 * 8);

  f32x4 acc[2][4] = {};
  float l[2] = {0.f, 0.f};

  // wave w stages segments {2w, 2w+1} of BOTH tiles of a phase:
  // g<4 -> K frag g at tile-offset 0..2047, g>=4 -> V frag g-4 at 2048..4095
  const int g0 = w * 2;

#define STAGE(BI, P) do { \
    const short* s0 = (g0 < 4) ? (Kh + (size_t)(2 * (P)) * 2048 + g0 * 512) \
                               : (Vh + (size_t)(2 * (P)) * 2048 + (g0 - 4) * 512); \
    GLD_LDS(s0 + sch,         &KV2[BI][g0 * 512]); \
    GLD_LDS(s0 + 512 + sch,   &KV2[BI][g0 * 512 + 512]); \
    const short* s1 = (g0 < 4) ? (Kh + (size_t)(2 * (P) + 1) * 2048 + g0 * 512) \
                               : (Vh + (size_t)(2 * (P) + 1) * 2048 + (g0 - 4) * 512); \
    GLD_LDS(s1 + sch,         &KV2[BI][4096 + g0 * 512]); \
    GLD_LDS(s1 + 512 + sch,   &KV2[BI][4096 + g0 * 512 + 512]); \
  } while (0)

  // one tile: ds_read K+V frags at LDS base KB, QK 8 MFMA, softmax, PV 8 MFMA
#define BODY1(KB, TT) do { \
    const short* Kb = (KB); \
    short8 kf[2][2], va[4]; \
    _Pragma("unroll") \
    for (int s = 0; s < 2; s++) \
      _Pragma("unroll") \
      for (int dc = 0; dc < 2; dc++) \
        kf[s][dc] = *(const short8*)(Kb + (s * 2 + dc) * 512 + rdo); \
    _Pragma("unroll") \
    for (int vs = 0; vs < 4; vs++) \
      va[vs] = *(const short8*)(Kb + 2048 + vs * 512 + rdo); \
    f32x4 st[2][2]; \
    _Pragma("unroll") \
    for (int u = 0; u < 2; u++) \
      _Pragma("unroll") \
      for (int s = 0; s < 2; s++) { \
        f32x4 z = {}; \
        z = __builtin_amdgcn_mfma_f32_16x16x32_bf16(kf[s][0], qa[u][0], z, 0, 0, 0); \
        st[u][s] = __builtin_amdgcn_mfma_f32_16x16x32_bf16(kf[s][1], qa[u][1], z, 0, 0, 0); \
      } \
    f32x4 cm[2], cb[2]; \
    _Pragma("unroll") \
    for (int s = 0; s < 2; s++) { \
      cm[s] = *(const f32x4*)(&cmL[(TT) * 32 + q4 * 4 + s * 16]); \
      cb[s] = *(const f32x4*)(&cbL[(TT) * 32 + q4 * 4 + s * 16]); \
    } \
    _Pragma("unroll") \
    for (int u = 0; u < 2; u++) { \
      unsigned pkd[2][2]; \
      _Pragma("unroll") \
      for (int s = 0; s < 2; s++) { \
        float e0 = __builtin_amdgcn_exp2f(st[u][s][0] * cm[s][0] + cb[s][0]); \
        float e1 = __builtin_amdgcn_exp2f(st[u][s][1] * cm[s][1] + cb[s][1]); \
        float e2 = __builtin_amdgcn_exp2f(st[u][s][2] * cm[s][2] + cb[s][2]); \
        float e3 = __builtin_amdgcn_exp2f(st[u][s][3] * cm[s][3] + cb[s][3]); \
        l[u] += (e0 + e1) + (e2 + e3); \
        unsigned p01, p23; \
        asm("v_cvt_pk_bf16_f32 %0, %1, %2" : "=v"(p01) : "v"(e0), "v"(e1)); \
        asm("v_cvt_pk_bf16_f32 %0, %1, %2" : "=v"(p23) : "v"(e2), "v"(e3)); \
        pkd[s][0] = p01; pkd[s][1] = p23; \
      } \
      union { i32x4 i; short8 s; } pb; \
      pb.i[0] = (int)pkd[0][0]; pb.i[1] = (int)pkd[0][1]; \
      pb.i[2] = (int)pkd[1][0]; pb.i[3] = (int)pkd[1][1]; \
      _Pragma("unroll") \
      for (int vs = 0; vs < 4; vs++) \
        acc[u][vs] = __builtin_amdgcn_mfma_f32_16x16x32_bf16(va[vs], pb.s, acc[u][vs], 0, 0, 0); \
    } \
  } while (0)

#define BODY(BI, P) do { \
    BODY1(&KV2[BI][0],    2 * (P)); \
    BODY1(&KV2[BI][4096], 2 * (P) + 1); \
  } while (0)

  __syncthreads();                                  // cmL/cbL visible
  asm volatile("s_waitcnt vmcnt(0)" ::: "memory");  // qa/mask loads drained
  STAGE(0, 0);
  asm volatile("s_waitcnt vmcnt(0)" ::: "memory");  // phase 0 landed
  __syncthreads();
  int cur = 0;
  for (int p = 0; p < 31; ++p) {
    STAGE(cur ^ 1, p + 1);          // stage next phase while computing current
    BODY(cur, p);
    asm volatile("s_waitcnt vmcnt(0)" ::: "memory");
    __syncthreads();                // staged data visible; readers done
    cur ^= 1;
  }
  BODY(cur, 31);
#undef STAGE
#undef BODY1
#undef BODY

  // epilogue: l reduce across q4 groups, normalize, store
#pragma unroll
  for (int u = 0; u < 2; u++) {
    float lu = l[u];
    lu += __shfl_xor(lu, 16);
    lu += __shfl_xor(lu, 32);
    float inv = 1.0f / lu;
    size_t row = (size_t)b * 2048 + qrow0 + u * 16 + c;
#pragma unroll
    for (int vs = 0; vs < 4; vs++) {
      f32x4 v = acc[u][vs];
      short4v pk;
#pragma unroll
      for (int r = 0; r < 4; r++) pk[r] = f2bf(v[r] * inv);
      *(short4v*)(AO + row * 1024 + h * 64 + vs * 16 + q4 * 4) = pk;
    }
  }
}

// ---------------- output projection v4 (R13-proven): t-split, 2 blocks/CU --
__global__ __launch_bounds__(256) void out_proj4(
    const short* __restrict__ AO, const short* __restrict__ Wot,
    const float* __restrict__ bo, float* __restrict__ out)
{
  const int t0 = blockIdx.x * 64;    // 64
  const int n0 = blockIdx.y * 128;   // 8
  const int tid = threadIdx.x, w = tid >> 6, lane = tid & 63;
  const int c = lane & 15, q4 = lane >> 4;
  const int wn = (w & 1) * 64, wt = (w >> 1) * 32;
  const int srow = lane >> 2, scol = (lane & 3) * 8;

  __shared__ __align__(16) short Al[2][2][4096];   // 128 n-rows x 32
  __shared__ __align__(16) short Bl[2][2][2048];   //  64 t-rows x 32

  f32x4 acc[4][2] = {};

#define PSTAGE(BUF, K0) do { \
    _Pragma("unroll") \
    for (int sub = 0; sub < 2; sub++) { \
      _Pragma("unroll") \
      for (int i = 0; i < 2; i++) { \
        int rg = (w * 2 + i) * 16; \
        GLD_LDS(Wot + (size_t)(n0 + rg + srow) * 1024 + (K0) + sub * 32 + scol, &Al[BUF][sub][rg * 32]); \
      } \
      int rb = w * 16; \
      GLD_LDS(AO + (size_t)(t0 + rb + srow) * 1024 + (K0) + sub * 32 + scol, &Bl[BUF][sub][rb * 32]); \
    } \
  } while (0)

#define PCOMP(BUF) do { \
    _Pragma("unroll") \
    for (int sub = 0; sub < 2; sub++) { \
      short8 a[4], bfr[2]; \
      _Pragma("unroll") \
      for (int i = 0; i < 4; i++) \
        a[i] = *(const short8*)(&Al[BUF][sub][(wn + i * 16 + c) * 32 + q4 * 8]); \
      _Pragma("unroll") \
      for (int j = 0; j < 2; j++) \
        bfr[j] = *(const short8*)(&Bl[BUF][sub][(wt + j * 16 + c) * 32 + q4 * 8]); \
      _Pragma("unroll") \
      for (int i = 0; i < 4; i++) \
        _Pragma("unroll") \
        for (int j = 0; j < 2; j++) \
          acc[i][j] = __builtin_amdgcn_mfma_f32_16x16x32_bf16(a[i], bfr[j], acc[i][j], 0, 0, 0); \
    } \
  } while (0)

  PSTAGE(0, 0);
  asm volatile("s_waitcnt vmcnt(0)" ::: "memory");
  __syncthreads();
  int cur = 0;
  for (int p = 0; p < 15; ++p) {
    PSTAGE(cur ^ 1, (p + 1) * 64);
    PCOMP(cur);
    asm volatile("s_waitcnt vmcnt(0)" ::: "memory");
    __syncthreads();
    cur ^= 1;
  }
  PCOMP(cur);
#undef PSTAGE
#undef PCOMP

#pragma unroll
  for (int i = 0; i < 4; i++)
#pragma unroll
    for (int j = 0; j < 2; j++) {
      int n = n0 + wn + i * 16 + q4 * 4;
      int trow = t0 + wt + j * 16 + c;
      f32x4 v = acc[i][j] + *(const f32x4*)(bo + n);
      *(f32x4*)(out + (size_t)trow * 1024 + n) = v;
    }
}

extern "C" void kernel_launch(void* const* d_in, const int* in_sizes, int n_in,
                              void* d_out, int out_size, void* d_ws, size_t ws_size,
                              hipStream_t stream)
{
  (void)in_sizes; (void)n_in; (void)out_size; (void)ws_size;
  const float* xq   = (const float*)d_in[0];
  const float* xk   = (const float*)d_in[1];
  const float* xv   = (const float*)d_in[2];
  const float* mask = (const float*)d_in[3];
  const float* wq   = (const float*)d_in[4];
  const float* wk   = (const float*)d_in[5];
  const float* wv   = (const float*)d_in[6];
  const float* wo   = (const float*)d_in[7];
  const float* bo   = (const float*)d_in[8];
  float* out = (float*)d_out;

  char* ws = (char*)d_ws;                    // needs 56 MB (Xb slot unused)
  short* Wall = (short*)(ws + (size_t)0);    // Wq/Wk/Wv contiguous
  short* Wot  = (short*)(ws + ((size_t)6 << 20));
  short* AO   = (short*)(ws + ((size_t)8 << 20));
  short* Qb   = (short*)(ws + ((size_t)32 << 20));
  short* Kt2  = (short*)(ws + ((size_t)40 << 20));  // K A-frag pre-tiled
  short* Vt2  = (short*)(ws + ((size_t)48 << 20));  // V^T pre-tiled, key-permuted

  prep_w<<<1024, 256, 0, stream>>>(wq, wk, wv, wo, Wall, Wot);
  proj_qkv5<<<dim3(32, 8, 3), 256, 0, stream>>>(xq, xk, xv, Wall, Qb, Kt2, Vt2);
  attn14<<<dim3(32, 16), 256, 0, stream>>>(Qb, Kt2, Vt2, mask, AO);
  out_proj4<<<dim3(64, 8), 256, 0, stream>>>(AO, Wot, bo, out);
}

// Round 15
// 216.965 us; speedup vs baseline: 1.2774x; 1.2774x over previous
//
#include <hip/hip_runtime.h>
#include <hip/hip_bf16.h>

// B=2, T=2048, DM=1024, H=16, DK=DV=64
// ws layout (56 MB):
//   [0,2)MB  Wqt bf16 [n=h*64+k][d]   [2,4) Wkt   [4,6) Wvt   [6,8) Wot [n=DM][k=H*DV]
//   [8,32)   Xb bf16 [3][4096][1024]  (xq,xk,xv cast)  -- dead after proj
//   [8,16)   AO bf16 [t][h*64+dv]     (ALIASES Xq slot; written by attn)
//   [32,40)  Qb bf16 [b][h][t][dk]
//   [40,48)  Kt2 bf16 [bh][64 ktile][s:1][dc:1][c:16][q4:4][j:8]  (K A-frag tiled)
//   [48,56)  Vt2 bf16 [bh][64 ktile][64 dv][32 k']  (V^T tiled, key-permuted sigma)
//
// FINAL (R15): revert to the R13-measured best (217.5us). The x-cast kernel
// stays: R12 (LDS-write fold) and R14 (register fold) both proved that
// folding the f32->bf16 cast into the fragment-ordered GEMM destroys
// coalescing (3.1M bank conflicts / uncoalesced scatter + drain, resp.).

typedef __attribute__((ext_vector_type(8))) short short8;
typedef __attribute__((ext_vector_type(4))) short short4v;
typedef __attribute__((ext_vector_type(4))) float f32x4;
typedef __attribute__((ext_vector_type(4))) int i32x4;

__device__ __forceinline__ short f2bf(float f) {
  union { float f; unsigned u; } v; v.f = f;
  unsigned r = v.u + 0x7FFFu + ((v.u >> 16) & 1u);  // RNE
  return (short)(r >> 16);
}

#define GLD_LDS(g, l) __builtin_amdgcn_global_load_lds( \
    (const __attribute__((address_space(1))) void*)(g), \
    (__attribute__((address_space(3))) void*)(l), 16, 0, 0)

// ---------------- fused prep: x cast | Wq/k/v transpose | Wo transpose -----
__global__ __launch_bounds__(256) void prep_all(
    const float* __restrict__ xq, const float* __restrict__ xk,
    const float* __restrict__ xv, const float* __restrict__ wq,
    const float* __restrict__ wk, const float* __restrict__ wv,
    const float* __restrict__ wo,
    short* __restrict__ Xb, short* __restrict__ Wall, short* __restrict__ Wot)
{
  const int bx = blockIdx.x, tid = threadIdx.x;
  __shared__ float Lt[64][65];
  if (bx < 6144) {                       // ---- x cast (2048 blocks per z)
    int z = bx >> 11;
    const float* x = z == 0 ? xq : (z == 1 ? xk : xv);
    size_t i = ((size_t)(bx & 2047) * 256 + tid) * 8;
    f32x4 f0 = *(const f32x4*)(x + i);
    f32x4 f1 = *(const f32x4*)(x + i + 4);
    short8 s;
#pragma unroll
    for (int j = 0; j < 4; j++) { s[j] = f2bf(f0[j]); s[4 + j] = f2bf(f1[j]); }
    *(short8*)(Xb + (size_t)z * 4194304 + i) = s;
  } else if (bx < 6912) {                // ---- Wq/k/v transpose (256 per z)
    int bz = bx - 6144;
    int z = bz >> 8, inner = bz & 255;
    const float* w = z == 0 ? wq : (z == 1 ? wk : wv);
    short* Wt = Wall + (size_t)z * 1048576;
    int h = inner >> 4, d0 = (inner & 15) * 64;
#pragma unroll
    for (int it = 0; it < 4; it++) {
      int e = tid + it * 256;
      int dl = e >> 4, k4 = (e & 15) * 4;
      f32x4 v = *(const f32x4*)(w + ((size_t)(h * 1024 + d0 + dl) * 64) + k4);
#pragma unroll
      for (int j = 0; j < 4; j++) Lt[dl][k4 + j] = v[j];
    }
    __syncthreads();
#pragma unroll
    for (int it = 0; it < 4; it++) {
      int e = tid + it * 256;
      int kl = e >> 4, dq = e & 15;
      short4v s;
#pragma unroll
      for (int j = 0; j < 4; j++) s[j] = f2bf(Lt[dq * 4 + j][kl]);
      *(short4v*)(Wt + (size_t)(h * 64 + kl) * 1024 + d0 + dq * 4) = s;
    }
  } else {                               // ---- Wo transpose (256 blocks)
    int bz = bx - 6912;
    int k0 = (bz >> 4) * 64, n0 = (bz & 15) * 64;
#pragma unroll
    for (int it = 0; it < 4; it++) {
      int e = tid + it * 256;
      int kl = e >> 4, n4 = (e & 15) * 4;
      f32x4 v = *(const f32x4*)(wo + (size_t)(k0 + kl) * 1024 + n0 + n4);
#pragma unroll
      for (int j = 0; j < 4; j++) Lt[kl][n4 + j] = v[j];
    }
    __syncthreads();
#pragma unroll
    for (int it = 0; it < 4; it++) {
      int e = tid + it * 256;
      int nl = e >> 4, kq = e & 15;
      short4v s;
#pragma unroll
      for (int j = 0; j < 4; j++) s[j] = f2bf(Lt[kq * 4 + j][nl]);
      *(short4v*)(Wot + (size_t)(n0 + nl) * 1024 + k0 + kq * 4) = s;
    }
  }
}

// ---------------- QKV projection v3 (R11/R13-proven): dbuf K=64 phases -----
__global__ __launch_bounds__(256) void proj_qkv3(
    const short* __restrict__ Xb, const short* __restrict__ Wall,
    short* __restrict__ Qb, short* __restrict__ Kt2, short* __restrict__ Vt2)
{
  const int z = blockIdx.z;
  const short* X  = Xb   + (size_t)z * 4194304;
  const short* Wt = Wall + (size_t)z * 1048576;

  const int t0 = blockIdx.x * 128;   // 32
  const int n0 = blockIdx.y * 128;   // 8
  const int tid = threadIdx.x, w = tid >> 6, lane = tid & 63;
  const int c = lane & 15, q4 = lane >> 4;
  const int wn = (w & 1) * 64, wt = (w >> 1) * 64;
  const int srow = lane >> 2, scol = (lane & 3) * 8;

  __shared__ __align__(16) short Al[2][2][4096];
  __shared__ __align__(16) short Bl[2][2][4096];

  f32x4 acc[4][4] = {};

#define PSTAGE(BUF, K0) do { \
    _Pragma("unroll") \
    for (int sub = 0; sub < 2; sub++) { \
      _Pragma("unroll") \
      for (int i = 0; i < 2; i++) { \
        int rg = (w * 2 + i) * 16; \
        GLD_LDS(Wt + (size_t)(n0 + rg + srow) * 1024 + (K0) + sub * 32 + scol, &Al[BUF][sub][rg * 32]); \
        GLD_LDS(X  + (size_t)(t0 + rg + srow) * 1024 + (K0) + sub * 32 + scol, &Bl[BUF][sub][rg * 32]); \
      } \
    } \
  } while (0)

#define PCOMP(BUF) do { \
    _Pragma("unroll") \
    for (int sub = 0; sub < 2; sub++) { \
      short8 a[4], bfr[4]; \
      if (z != 2) { \
        _Pragma("unroll") \
        for (int i = 0; i < 4; i++) \
          a[i] = *(const short8*)(&Al[BUF][sub][(wn + i * 16 + c) * 32 + q4 * 8]); \
        _Pragma("unroll") \
        for (int j = 0; j < 4; j++) \
          bfr[j] = *(const short8*)(&Bl[BUF][sub][(wt + j * 16 + c) * 32 + q4 * 8]); \
      } else { \
        _Pragma("unroll") \
        for (int i = 0; i < 4; i++) \
          a[i] = *(const short8*)(&Bl[BUF][sub][(wt + i * 16 + c) * 32 + q4 * 8]); \
        _Pragma("unroll") \
        for (int j = 0; j < 4; j++) \
          bfr[j] = *(const short8*)(&Al[BUF][sub][(wn + j * 16 + c) * 32 + q4 * 8]); \
      } \
      _Pragma("unroll") \
      for (int i = 0; i < 4; i++) \
        _Pragma("unroll") \
        for (int j = 0; j < 4; j++) \
          acc[i][j] = __builtin_amdgcn_mfma_f32_16x16x32_bf16(a[i], bfr[j], acc[i][j], 0, 0, 0); \
    } \
  } while (0)

  PSTAGE(0, 0);
  asm volatile("s_waitcnt vmcnt(0)" ::: "memory");
  __syncthreads();
  int cur = 0;
  for (int p = 0; p < 15; ++p) {
    PSTAGE(cur ^ 1, (p + 1) * 64);  // stage next phase while computing current
    PCOMP(cur);
    asm volatile("s_waitcnt vmcnt(0)" ::: "memory");
    __syncthreads();
    cur ^= 1;
  }
  PCOMP(cur);
#undef PSTAGE
#undef PCOMP

  if (z != 2) {
#pragma unroll
    for (int i = 0; i < 4; i++)
#pragma unroll
      for (int j = 0; j < 4; j++) {
        int n = n0 + wn + i * 16 + q4 * 4;     // h*64 + d base (+4 consecutive)
        int trow = t0 + wt + j * 16 + c;
        int b = trow >> 11, t = trow & 2047;
        int h = n >> 6, cc = n & 63;
        int bh = b * 16 + h;
        f32x4 v = acc[i][j];
        short4v pk;
#pragma unroll
        for (int r = 0; r < 4; r++) pk[r] = f2bf(v[r]);
        if (z == 0) {
          *(short4v*)(Qb + (size_t)(bh * 2048 + t) * 64 + cc) = pk;
        } else {
          // Kt2: cc%4==0 -> the 4 d-values share chunk bits -> one short4
          int t5 = t & 31, s_ = t5 >> 4, c_ = t5 & 15;
          size_t base = (size_t)bh * 131072 + (t >> 5) * 2048;
          size_t off = base + ((s_ * 2 + (cc >> 5)) * 16 + c_) * 32 +
                       ((cc >> 3) & 3) * 8 + (cc & 7);
          *(short4v*)(Kt2 + off) = pk;
        }
      }
  } else {
    // swapped operands: output quad runs along t (t%4==0), col = n
#pragma unroll
    for (int i = 0; i < 4; i++)
#pragma unroll
      for (int j = 0; j < 4; j++) {
        int tq = t0 + wt + i * 16 + q4 * 4;    // 4 consecutive keys
        int n = n0 + wn + j * 16 + c;
        int b = tq >> 11, t = tq & 2047;
        int h = n >> 6, cc = n & 63;
        int bh = b * 16 + h;
        int t5 = t & 31;                        // t5 % 4 == 0
        int kpb = ((t5 >> 2) & 3) * 8 + ((t5 >> 4) & 1) * 4;  // kp(t5+r)=kpb+r
        size_t base = (size_t)bh * 131072 + (t >> 5) * 2048;
        f32x4 v = acc[i][j];
        short4v pk;
#pragma unroll
        for (int r = 0; r < 4; r++) pk[r] = f2bf(v[r]);
        *(short4v*)(Vt2 + base + (size_t)cc * 32 + kpb) = pk;
      }
  }
}

// ---------------- fused attention v14 (R9/R11/R13-proven, 52.1us) ----------
__global__ __launch_bounds__(256, 2) void attn14(
    const short* __restrict__ Qb, const short* __restrict__ Kt2,
    const short* __restrict__ Vt2, const float* __restrict__ mask,
    short* __restrict__ AO)
{
  const int bh = blockIdx.x;
  const int tblk = blockIdx.y;
  const int b = bh >> 4, h = bh & 15;
  const short* Qh = Qb  + (size_t)bh * 131072;
  const short* Kh = Kt2 + (size_t)bh * 131072;
  const short* Vh = Vt2 + (size_t)bh * 131072;

  const int tid = threadIdx.x, w = tid >> 6, lane = tid & 63;
  const int c = lane & 15, q4 = lane >> 4;
  const int qrow0 = tblk * 128 + w * 32;

  // LDS: 2 phase-buffers x 2 tiles x [K segs 0..3 | V segs 4..7] = 32 KB
  __shared__ __align__(16) short KV2[2][8192];
  __shared__ __align__(16) float cmL[2048];     // mask * log2e/64
  __shared__ __align__(16) float cbL[2048];     // (mask-1) * 240

  const int ch = c * 4 + q4;
  const int rdo = (ch ^ ((ch >> 3) & 3)) * 8;   // swizzled ds_read offset
  const int sch = (lane ^ ((lane >> 3) & 3)) * 8;

  // mask coefficient precompute (8 elems/thread)
  {
    const float LOG2E_64c = 1.44269504088896f * 0.015625f;
    f32x4 m0 = *(const f32x4*)(mask + b * 2048 + tid * 8);
    f32x4 m1 = *(const f32x4*)(mask + b * 2048 + tid * 8 + 4);
    *(f32x4*)(&cmL[tid * 8])     = m0 * LOG2E_64c;
    *(f32x4*)(&cmL[tid * 8 + 4]) = m1 * LOG2E_64c;
    *(f32x4*)(&cbL[tid * 8])     = (m0 - 1.0f) * 240.0f;
    *(f32x4*)(&cbL[tid * 8 + 4]) = (m1 - 1.0f) * 240.0f;
  }

  // Q fragments for the whole loop (B-operand: n=qrow=c, k=q4*8+j)
  short8 qa[2][2];
#pragma unroll
  for (int u = 0; u < 2; u++)
#pragma unroll
    for (int dc = 0; dc < 2; dc++)
      qa[u][dc] = *(const short8*)(Qh + (size_t)(qrow0 + u * 16 + c) * 64 + dc * 32 + q4 * 8);

  f32x4 acc[2][4] = {};
  float l[2] = {0.f, 0.f};

  // wave w stages segments {2w, 2w+1} of BOTH tiles of a phase:
  // g<4 -> K frag g at tile-offset 0..2047, g>=4 -> V frag g-4 at 2048..4095
  const int g0 = w * 2;

#define STAGE(BI, P) do { \
    const short* s0 = (g0 < 4) ? (Kh + (size_t)(2 * (P)) * 2048 + g0 * 512) \
                               : (Vh + (size_t)(2 * (P)) * 2048 + (g0 - 4) * 512); \
    GLD_LDS(s0 + sch,         &KV2[BI][g0 * 512]); \
    GLD_LDS(s0 + 512 + sch,   &KV2[BI][g0 * 512 + 512]); \
    const short* s1 = (g0 < 4) ? (Kh + (size_t)(2 * (P) + 1) * 2048 + g0 * 512) \
                               : (Vh + (size_t)(2 * (P) + 1) * 2048 + (g0 - 4) * 512); \
    GLD_LDS(s1 + sch,         &KV2[BI][4096 + g0 * 512]); \
    GLD_LDS(s1 + 512 + sch,   &KV2[BI][4096 + g0 * 512 + 512]); \
  } while (0)

  // one tile: ds_read K+V frags at LDS base KB, QK 8 MFMA, softmax, PV 8 MFMA
#define BODY1(KB, TT) do { \
    const short* Kb = (KB); \
    short8 kf[2][2], va[4]; \
    _Pragma("unroll") \
    for (int s = 0; s < 2; s++) \
      _Pragma("unroll") \
      for (int dc = 0; dc < 2; dc++) \
        kf[s][dc] = *(const short8*)(Kb + (s * 2 + dc) * 512 + rdo); \
    _Pragma("unroll") \
    for (int vs = 0; vs < 4; vs++) \
      va[vs] = *(const short8*)(Kb + 2048 + vs * 512 + rdo); \
    f32x4 st[2][2]; \
    _Pragma("unroll") \
    for (int u = 0; u < 2; u++) \
      _Pragma("unroll") \
      for (int s = 0; s < 2; s++) { \
        f32x4 z = {}; \
        z = __builtin_amdgcn_mfma_f32_16x16x32_bf16(kf[s][0], qa[u][0], z, 0, 0, 0); \
        st[u][s] = __builtin_amdgcn_mfma_f32_16x16x32_bf16(kf[s][1], qa[u][1], z, 0, 0, 0); \
      } \
    f32x4 cm[2], cb[2]; \
    _Pragma("unroll") \
    for (int s = 0; s < 2; s++) { \
      cm[s] = *(const f32x4*)(&cmL[(TT) * 32 + q4 * 4 + s * 16]); \
      cb[s] = *(const f32x4*)(&cbL[(TT) * 32 + q4 * 4 + s * 16]); \
    } \
    _Pragma("unroll") \
    for (int u = 0; u < 2; u++) { \
      unsigned pkd[2][2]; \
      _Pragma("unroll") \
      for (int s = 0; s < 2; s++) { \
        float e0 = __builtin_amdgcn_exp2f(st[u][s][0] * cm[s][0] + cb[s][0]); \
        float e1 = __builtin_amdgcn_exp2f(st[u][s][1] * cm[s][1] + cb[s][1]); \
        float e2 = __builtin_amdgcn_exp2f(st[u][s][2] * cm[s][2] + cb[s][2]); \
        float e3 = __builtin_amdgcn_exp2f(st[u][s][3] * cm[s][3] + cb[s][3]); \
        l[u] += (e0 + e1) + (e2 + e3); \
        unsigned p01, p23; \
        asm("v_cvt_pk_bf16_f32 %0, %1, %2" : "=v"(p01) : "v"(e0), "v"(e1)); \
        asm("v_cvt_pk_bf16_f32 %0, %1, %2" : "=v"(p23) : "v"(e2), "v"(e3)); \
        pkd[s][0] = p01; pkd[s][1] = p23; \
      } \
      union { i32x4 i; short8 s; } pb; \
      pb.i[0] = (int)pkd[0][0]; pb.i[1] = (int)pkd[0][1]; \
      pb.i[2] = (int)pkd[1][0]; pb.i[3] = (int)pkd[1][1]; \
      _Pragma("unroll") \
      for (int vs = 0; vs < 4; vs++) \
        acc[u][vs] = __builtin_amdgcn_mfma_f32_16x16x32_bf16(va[vs], pb.s, acc[u][vs], 0, 0, 0); \
    } \
  } while (0)

#define BODY(BI, P) do { \
    BODY1(&KV2[BI][0],    2 * (P)); \
    BODY1(&KV2[BI][4096], 2 * (P) + 1); \
  } while (0)

  __syncthreads();                                  // cmL/cbL visible
  asm volatile("s_waitcnt vmcnt(0)" ::: "memory");  // qa/mask loads drained
  STAGE(0, 0);
  asm volatile("s_waitcnt vmcnt(0)" ::: "memory");  // phase 0 landed
  __syncthreads();
  int cur = 0;
  for (int p = 0; p < 31; ++p) {
    STAGE(cur ^ 1, p + 1);          // stage next phase while computing current
    BODY(cur, p);
    asm volatile("s_waitcnt vmcnt(0)" ::: "memory");
    __syncthreads();                // staged data visible; readers done
    cur ^= 1;
  }
  BODY(cur, 31);
#undef STAGE
#undef BODY1
#undef BODY

  // epilogue: l reduce across q4 groups, normalize, store
#pragma unroll
  for (int u = 0; u < 2; u++) {
    float lu = l[u];
    lu += __shfl_xor(lu, 16);
    lu += __shfl_xor(lu, 32);
    float inv = 1.0f / lu;
    size_t row = (size_t)b * 2048 + qrow0 + u * 16 + c;
#pragma unroll
    for (int vs = 0; vs < 4; vs++) {
      f32x4 v = acc[u][vs];
      short4v pk;
#pragma unroll
      for (int r = 0; r < 4; r++) pk[r] = f2bf(v[r] * inv);
      *(short4v*)(AO + row * 1024 + h * 64 + vs * 16 + q4 * 4) = pk;
    }
  }
}

// ---------------- output projection v4 (R13-proven): t-split, 2 blocks/CU --
__global__ __launch_bounds__(256) void out_proj4(
    const short* __restrict__ AO, const short* __restrict__ Wot,
    const float* __restrict__ bo, float* __restrict__ out)
{
  const int t0 = blockIdx.x * 64;    // 64
  const int n0 = blockIdx.y * 128;   // 8
  const int tid = threadIdx.x, w = tid >> 6, lane = tid & 63;
  const int c = lane & 15, q4 = lane >> 4;
  const int wn = (w & 1) * 64, wt = (w >> 1) * 32;
  const int srow = lane >> 2, scol = (lane & 3) * 8;

  __shared__ __align__(16) short Al[2][2][4096];   // 128 n-rows x 32
  __shared__ __align__(16) short Bl[2][2][2048];   //  64 t-rows x 32

  f32x4 acc[4][2] = {};

#define PSTAGE(BUF, K0) do { \
    _Pragma("unroll") \
    for (int sub = 0; sub < 2; sub++) { \
      _Pragma("unroll") \
      for (int i = 0; i < 2; i++) { \
        int rg = (w * 2 + i) * 16; \
        GLD_LDS(Wot + (size_t)(n0 + rg + srow) * 1024 + (K0) + sub * 32 + scol, &Al[BUF][sub][rg * 32]); \
      } \
      int rb = w * 16; \
      GLD_LDS(AO + (size_t)(t0 + rb + srow) * 1024 + (K0) + sub * 32 + scol, &Bl[BUF][sub][rb * 32]); \
    } \
  } while (0)

#define PCOMP(BUF) do { \
    _Pragma("unroll") \
    for (int sub = 0; sub < 2; sub++) { \
      short8 a[4], bfr[2]; \
      _Pragma("unroll") \
      for (int i = 0; i < 4; i++) \
        a[i] = *(const short8*)(&Al[BUF][sub][(wn + i * 16 + c) * 32 + q4 * 8]); \
      _Pragma("unroll") \
      for (int j = 0; j < 2; j++) \
        bfr[j] = *(const short8*)(&Bl[BUF][sub][(wt + j * 16 + c) * 32 + q4 * 8]); \
      _Pragma("unroll") \
      for (int i = 0; i < 4; i++) \
        _Pragma("unroll") \
        for (int j = 0; j < 2; j++) \
          acc[i][j] = __builtin_amdgcn_mfma_f32_16x16x32_bf16(a[i], bfr[j], acc[i][j], 0, 0, 0); \
    } \
  } while (0)

  PSTAGE(0, 0);
  asm volatile("s_waitcnt vmcnt(0)" ::: "memory");
  __syncthreads();
  int cur = 0;
  for (int p = 0; p < 15; ++p) {
    PSTAGE(cur ^ 1, (p + 1) * 64);
    PCOMP(cur);
    asm volatile("s_waitcnt vmcnt(0)" ::: "memory");
    __syncthreads();
    cur ^= 1;
  }
  PCOMP(cur);
#undef PSTAGE
#undef PCOMP

#pragma unroll
  for (int i = 0; i < 4; i++)
#pragma unroll
    for (int j = 0; j < 2; j++) {
      int n = n0 + wn + i * 16 + q4 * 4;
      int trow = t0 + wt + j * 16 + c;
      f32x4 v = acc[i][j] + *(const f32x4*)(bo + n);
      *(f32x4*)(out + (size_t)trow * 1024 + n) = v;
    }
}

extern "C" void kernel_launch(void* const* d_in, const int* in_sizes, int n_in,
                              void* d_out, int out_size, void* d_ws, size_t ws_size,
                              hipStream_t stream)
{
  (void)in_sizes; (void)n_in; (void)out_size; (void)ws_size;
  const float* xq   = (const float*)d_in[0];
  const float* xk   = (const float*)d_in[1];
  const float* xv   = (const float*)d_in[2];
  const float* mask = (const float*)d_in[3];
  const float* wq   = (const float*)d_in[4];
  const float* wk   = (const float*)d_in[5];
  const float* wv   = (const float*)d_in[6];
  const float* wo   = (const float*)d_in[7];
  const float* bo   = (const float*)d_in[8];
  float* out = (float*)d_out;

  char* ws = (char*)d_ws;                    // needs 56 MB
  short* Wall = (short*)(ws + (size_t)0);    // Wq/Wk/Wv contiguous
  short* Wot  = (short*)(ws + ((size_t)6 << 20));
  short* Xb   = (short*)(ws + ((size_t)8 << 20));   // 24 MB, dead after proj
  short* AO   = (short*)(ws + ((size_t)8 << 20));   // aliases Xq slot (8 MB)
  short* Qb   = (short*)(ws + ((size_t)32 << 20));
  short* Kt2  = (short*)(ws + ((size_t)40 << 20));  // K A-frag pre-tiled
  short* Vt2  = (short*)(ws + ((size_t)48 << 20));  // V^T pre-tiled, key-permuted

  prep_all<<<7168, 256, 0, stream>>>(xq, xk, xv, wq, wk, wv, wo, Xb, Wall, Wot);
  proj_qkv3<<<dim3(32, 8, 3), 256, 0, stream>>>(Xb, Wall, Qb, Kt2, Vt2);
  attn14<<<dim3(32, 16), 256, 0, stream>>>(Qb, Kt2, Vt2, mask, AO);
  out_proj4<<<dim3(64, 8), 256, 0, stream>>>(AO, Wot, bo, out);
}